// Round 7
// baseline (684.216 us; speedup 1.0000x reference)
//
#include <hip/hip_runtime.h>
#include <hip/hip_cooperative_groups.h>
#include <math.h>

namespace cg = cooperative_groups;

#define NPIX (480*640)
#define MDIM 960
#define MPIX (MDIM*MDIM)
#define PACK_M 307201u
#define NSLAB 8
#define SLABW 488            // 480 used + 8 pad: de-aligns banks across slabs

// ws layout (u32/f32 units from base)
#define CNT_OFF    0         // u32[10000]
#define SCAL_OFF   10000     // f32[16]  (contiguous after cnt: phase 0 zeroes both)
#define OFFS_OFF   10016     // u32[10001]
#define SM_OFF     20024     // f32[70000]
#define PACK_OFF   90024     // u32[NPIX]
#define PAY_OFF    397224    // f32[8*NPIX]; 397224*4 % 16 == 0

// output layout (floats)
#define OUT_FPMAP 0
#define OUT_MAP   10000
#define OUT_POSE  (10000 + 9*MPIX)

// bilinear sample of the (implicit, mostly-zero) agent_view at normalized coords
__device__ __forceinline__ void sample_agent(float gxv, float gyv,
                                             float ct, float sn,
                                             const float* __restrict__ sm,
                                             float rot[7]) {
    float u = ct*gxv - sn*gyv;
    float v = sn*gxv + ct*gyv;
    float xim = ((u + 1.0f)*0.5f)*959.0f;
    float yim = ((v + 1.0f)*0.5f)*959.0f;
    float x0 = floorf(xim), y0 = floorf(yim);
    #pragma unroll
    for (int ty = 0; ty <= 1; ty++) {
        float yy = y0 + (float)ty;
        if (yy < 480.0f || yy >= 580.0f) continue;   // region rows [480,580)
        float wy = 1.0f - fabsf(yim - yy);
        int yi = (int)yy - 480;
        #pragma unroll
        for (int tx = 0; tx <= 1; tx++) {
            float xx = x0 + (float)tx;
            if (xx < 430.0f || xx >= 530.0f) continue;  // region cols [430,530)
            float w = (1.0f - fabsf(xim - xx)) * wy;
            int o = yi*100 + ((int)xx - 430);
            #pragma unroll
            for (int k = 0; k < 7; k++) rot[k] += sm[k*10000 + o] * w;
        }
    }
}

__device__ __forceinline__ void pixel_ts(float xim, float yim, float ct, float sn,
                                         const float* __restrict__ sm, float ts[7]) {
    const float step = 2.0f/959.0f;
    float x0 = floorf(xim), y0 = floorf(yim);
    #pragma unroll
    for (int ty = 0; ty <= 1; ty++) {
        float yy = y0 + (float)ty;
        if (yy < 0.0f || yy > 959.0f) continue;
        float wy = 1.0f - fabsf(yim - yy);
        #pragma unroll
        for (int tx = 0; tx <= 1; tx++) {
            float xx = x0 + (float)tx;
            if (xx < 0.0f || xx > 959.0f) continue;
            float w = (1.0f - fabsf(xim - xx)) * wy;
            float rot[7] = {0,0,0,0,0,0,0};
            float gx1 = xx*step - 1.0f;
            float gy1 = yy*step - 1.0f;
            sample_agent(gx1, gy1, ct, sn, sm, rot);
            #pragma unroll
            for (int k = 0; k < 7; k++) ts[k] += rot[k]*w;
        }
    }
}

__global__ __launch_bounds__(256, 4) void mega_kernel(
    const float* __restrict__ obs, const float* pose_obs,
    const float* __restrict__ maps_last, const float* poses_last,
    unsigned* __restrict__ cnt, float* __restrict__ scal,
    unsigned* __restrict__ offs, float* __restrict__ sm,
    unsigned* __restrict__ pack, float4* __restrict__ pay,
    float* __restrict__ out_fp, float* __restrict__ out_map,
    float* __restrict__ out_pose, float fcam)
{
    cg::grid_group grid = cg::this_grid();
    __shared__ float sh[NSLAB*SLABW];
    const int tid = threadIdx.x;
    const int g = blockIdx.x*256 + tid;
    const int nthr = gridDim.x*256;

    // ---------- phase 0: zero cnt + scal (contiguous 10016 u32) ----------
    for (int idx = g; idx < 10016; idx += nthr) cnt[idx] = 0u;
    grid.sync();

    // ---------- phase 1: count + ks + pose ----------
    {
        float m0 = 0.0f, m1 = 0.0f, m2 = 0.0f, m3 = 0.0f;
        for (int q4 = g; q4 < 76800; q4 += nthr) {
            int p = q4*4;
            int i = p / 640, j0 = p - i*640;       // 4 pixels share a row
            float4 d4 = *(const float4*)(obs + 3*NPIX + p);
            float dv[4] = {d4.x, d4.y, d4.z, d4.w};
            #pragma unroll
            for (int q = 0; q < 4; q++) {
                float d = dv[q];
                float X = ((float)(j0+q) - 319.5f) * d / fcam + 250.0f;
                float Z = ((float)(479 - i) - 239.5f) * d / fcam + 88.0f;
                float xs = ((X/5.0f - 50.0f)/100.0f)*2.0f;
                float ys = ((d/5.0f - 50.0f)/100.0f)*2.0f;
                float zs = ((Z/5.0f - 32.0f)/80.0f)*2.0f;
                float pos0 = (xs*100.0f)/2.0f + 50.0f;
                float pos1 = (ys*100.0f)/2.0f + 50.0f;
                float pos2 = (zs*80.0f)/2.0f + 40.0f;
                int bx = (int)floorf(pos0), by = (int)floorf(pos1), bz = (int)floorf(pos2);
                unsigned pk = 0xFFFFFFFFu;
                if (bx >= 0 && bx <= 99 && by >= 0 && by <= 99 && bz >= 0 && bz <= 79) {
                    unsigned b = (unsigned)(bx*100 + by);
                    unsigned rank = atomicAdd(&cnt[b], 1u);
                    pk = b * PACK_M + rank;
                }
                pack[p+q] = pk;
            }
            float4 a  = *(const float4*)(obs + 4*NPIX + p);
            float4 b4 = *(const float4*)(obs + 5*NPIX + p);
            float4 c4 = *(const float4*)(obs + 6*NPIX + p);
            float4 e4 = *(const float4*)(obs + 7*NPIX + p);
            m0 = fmaxf(m0, fmaxf(fmaxf(a.x,a.y),   fmaxf(a.z,a.w)));
            m1 = fmaxf(m1, fmaxf(fmaxf(b4.x,b4.y), fmaxf(b4.z,b4.w)));
            m2 = fmaxf(m2, fmaxf(fmaxf(c4.x,c4.y), fmaxf(c4.z,c4.w)));
            m3 = fmaxf(m3, fmaxf(fmaxf(e4.x,e4.y), fmaxf(e4.z,e4.w)));
        }
        #pragma unroll
        for (int off = 32; off > 0; off >>= 1) {
            m0 = fmaxf(m0, __shfl_down(m0, off, 64));
            m1 = fmaxf(m1, __shfl_down(m1, off, 64));
            m2 = fmaxf(m2, __shfl_down(m2, off, 64));
            m3 = fmaxf(m3, __shfl_down(m3, off, 64));
        }
        if ((tid & 63) == 0) {   // obs values nonnegative: int-bits compare as float
            atomicMax((int*)&scal[4], __float_as_int(m0));
            atomicMax((int*)&scal[5], __float_as_int(m1));
            atomicMax((int*)&scal[6], __float_as_int(m2));
            atomicMax((int*)&scal[7], __float_as_int(m3));
        }
        if (g == 0) {
            const float DEGc = 57.29577951308232f;
            float th = poses_last[2] / DEGc;
            float s = sinf(th), c = cosf(th);
            float ny = poses_last[1] + pose_obs[0]*s + pose_obs[1]*c;
            float nx = poses_last[0] + pose_obs[0]*c - pose_obs[1]*s;
            float nt = poses_last[2] + pose_obs[2]*DEGc;
            nt = fmodf(nt - 180.0f, 360.0f) + 180.0f;
            nt = fmodf(nt + 180.0f, 360.0f) - 180.0f;
            out_pose[0] = nx; out_pose[1] = ny; out_pose[2] = nt;
            out_pose[3] = nx; out_pose[4] = ny; out_pose[5] = nt;
            float sx = -((nx*100.0f)/5.0f - 480.0f)/480.0f;
            float sy = -((ny*100.0f)/5.0f - 480.0f)/480.0f;
            float sth = ((90.0f - nt) * 3.14159265358979323846f) / 180.0f;
            scal[0] = cosf(sth);
            scal[1] = sinf(sth);
            scal[2] = sx;
            scal[3] = sy;
        }
    }
    grid.sync();

    // ---------- phase 2: exclusive scan of cnt (WG 0 only) ----------
    if (blockIdx.x == 0) {
        int lane = tid & 63, wave = tid >> 6;
        unsigned* shu = (unsigned*)sh;
        unsigned sum = 0;
        #pragma unroll 4
        for (int q = 0; q < 40; q++) {
            int idx = tid*40 + q;
            if (idx < 10000) sum += cnt[idx];
        }
        unsigned incl = sum;
        #pragma unroll
        for (int off = 1; off < 64; off <<= 1) {
            unsigned u = (unsigned)__shfl_up((int)incl, off, 64);
            if (lane >= off) incl += u;
        }
        if (lane == 63) shu[wave] = incl;
        __syncthreads();
        unsigned pre = 0;
        for (int w = 0; w < wave; w++) pre += shu[w];
        unsigned excl = pre + incl - sum;
        unsigned run = excl;
        #pragma unroll 4
        for (int q = 0; q < 40; q++) {
            int idx = tid*40 + q;
            if (idx < 10000) { offs[idx] = run; run += cnt[idx]; }
        }
        if (tid == 255) offs[10000] = excl;  // grand total (tids 250..255 sum 0)
    }
    grid.sync();

    // ---------- phase 3: scatter (atomic-free) ----------
    for (int q4 = g; q4 < 76800; q4 += nthr) {
        int p = q4*4;
        int i = p / 640, j0 = p - i*640;
        uint4 pk4 = *(const uint4*)(pack + p);
        unsigned pks[4] = {pk4.x, pk4.y, pk4.z, pk4.w};
        float4 d4  = *(const float4*)(obs + 3*NPIX + p);
        float4 f14 = *(const float4*)(obs + 4*NPIX + p);
        float4 f24 = *(const float4*)(obs + 5*NPIX + p);
        float4 f34 = *(const float4*)(obs + 6*NPIX + p);
        float4 f44 = *(const float4*)(obs + 7*NPIX + p);
        float4 f54 = *(const float4*)(obs + 8*NPIX + p);
        float dv[4] = {d4.x, d4.y, d4.z, d4.w};
        float f1[4] = {f14.x, f14.y, f14.z, f14.w};
        float f2[4] = {f24.x, f24.y, f24.z, f24.w};
        float f3[4] = {f34.x, f34.y, f34.z, f34.w};
        float f4v[4] = {f44.x, f44.y, f44.z, f44.w};
        float f5[4] = {f54.x, f54.y, f54.z, f54.w};
        #pragma unroll
        for (int q = 0; q < 4; q++) {
            unsigned pk = pks[q];
            if (pk == 0xFFFFFFFFu) continue;
            unsigned b = pk / PACK_M;
            unsigned rank = pk - b * PACK_M;
            unsigned k = offs[b] + rank;
            float d = dv[q];
            float X = ((float)(j0+q) - 319.5f) * d / fcam + 250.0f;
            float Z = ((float)(479 - i) - 239.5f) * d / fcam + 88.0f;
            float xs = ((X/5.0f - 50.0f)/100.0f)*2.0f;
            float ys = ((d/5.0f - 50.0f)/100.0f)*2.0f;
            float zs = ((Z/5.0f - 32.0f)/80.0f)*2.0f;
            float pos0 = (xs*100.0f)/2.0f + 50.0f;
            float pos1 = (ys*100.0f)/2.0f + 50.0f;
            float pos2 = (zs*80.0f)/2.0f + 40.0f;
            pay[2*k + 0] = make_float4(pos0, pos1, pos2, f1[q]);
            pay[2*k + 1] = make_float4(f2[q], f3[q], f4v[q], f5[q]);
        }
    }
    grid.sync();

    // ---------- phase 4: gather per column; 8 private LDS sub-slabs ----------
    for (int t = blockIdx.x; t < 10000; t += gridDim.x) {
        int x = t % 100, y = t / 100;
        for (int q = tid; q < NSLAB*SLABW; q += 256) sh[q] = 0.0f;
        __syncthreads();
        if (x >= 1 && y >= 1) {        // x==0 or y==0: no in-bounds corners
            int wave = tid >> 6, lane = tid & 63;
            int bx = x - 1 + (wave & 1);
            int by = y - 1 + (wave >> 1);
            int b = bx*100 + by;
            float* slab = sh + (size_t)(wave*2 + (lane >> 5)) * SLABW;
            unsigned s = offs[b], e = offs[b+1];
            for (unsigned k = s + lane; k < e; k += 64) {
                float4 a  = pay[2*k + 0];
                float4 q2 = pay[2*k + 1];
                // weights replicate reference order: ((1*(1-|d0|))*(1-|d1|))*(1-|d2|)
                float w0 = 1.0f - fabsf(a.x - (float)x);
                float w1 = 1.0f - fabsf(a.y - (float)y);
                float w01 = w0 * w1;
                float bzf = floorf(a.z);
                #pragma unroll
                for (int c2 = 0; c2 <= 1; c2++) {
                    float p2 = bzf + (float)c2;
                    if (!(p2 > 0.0f && p2 < 80.0f)) continue;
                    float w = w01 * (1.0f - fabsf(a.z - p2));
                    int zi = (int)p2;
                    int zb = zi * 6;
                    atomicAdd(&slab[zb + 0], w);
                    if (zi >= 13 && zi < 25) {   // ch1-5 never read outside [13,25)
                        atomicAdd(&slab[zb + 1], w*a.w);
                        atomicAdd(&slab[zb + 2], w*q2.x);
                        atomicAdd(&slab[zb + 3], w*q2.y);
                        atomicAdd(&slab[zb + 4], w*q2.z);
                        atomicAdd(&slab[zb + 5], w*q2.w);
                    }
                }
            }
        }
        __syncthreads();
        // merge 8 sub-slabs into slab 0
        for (int q = tid; q < 480; q += 256) {
            float s2 = sh[q];
            #pragma unroll
            for (int r = 1; r < NSLAB; r++) s2 += sh[r*SLABW + q];
            sh[q] = s2;
        }
        __syncthreads();
        if (tid < 64) {
            int z = tid;                 // z in [0,64); [64,80) folded by lanes 0..15
            float r0 = rintf(sh[z*6 + 0]);
            float all0 = r0;
            if (tid < 16) all0 += rintf(sh[(z + 64)*6 + 0]);
            bool inb = (z >= 13 && z < 25);
            float a0 = inb ? r0 : 0.0f;
            float a1 = inb ? rintf(sh[z*6 + 1]) : 0.0f;
            float a2 = inb ? rintf(sh[z*6 + 2]) : 0.0f;
            float a3 = inb ? rintf(sh[z*6 + 3]) : 0.0f;
            float a4 = inb ? rintf(sh[z*6 + 4]) : 0.0f;
            float a5 = inb ? rintf(sh[z*6 + 5]) : 0.0f;
            #pragma unroll
            for (int off = 32; off > 0; off >>= 1) {
                all0 += __shfl_down(all0, off, 64);
                a0 += __shfl_down(a0, off, 64);
                a1 += __shfl_down(a1, off, 64);
                a2 += __shfl_down(a2, off, 64);
                a3 += __shfl_down(a3, off, 64);
                a4 += __shfl_down(a4, off, 64);
                a5 += __shfl_down(a5, off, 64);
            }
            if (tid == 0) {
                float fp = fminf(a0, 1.0f);
                float ex = fminf(all0, 1.0f);
                sm[0*10000 + t] = fp;
                sm[1*10000 + t] = ex;
                sm[2*10000 + t] = fminf(a1/5.0f, 1.0f);
                sm[3*10000 + t] = fminf(a2/5.0f, 1.0f);
                sm[4*10000 + t] = fminf(a3/5.0f, 1.0f);
                sm[5*10000 + t] = fminf(a4/5.0f, 1.0f);
                sm[6*10000 + t] = fminf(a5/5.0f, 1.0f);
                out_fp[t] = fp;
            }
        }
        __syncthreads();
    }
    grid.sync();

    // ---------- phase 5: final map update (4 px/thread) ----------
    {
        float ct = scal[0], sn = scal[1], sx = scal[2], sy = scal[3];
        float ks0 = scal[4], ks1 = scal[5], ks2 = scal[6], ks3 = scal[7];
        const float step = 2.0f/959.0f;
        for (int q4 = g; q4 < 230400; q4 += nthr) {
            int p = q4*4;
            int y = p / MDIM, xp = p - y*MDIM;   // 4 pixels share a row
            float gyv = (float)y*step - 1.0f;
            float v = gyv + sy;
            float yim = ((v + 1.0f)*0.5f)*959.0f;
            float gyc = yim*step - 1.0f;
            float xims[4];
            bool act[4];
            bool any = false;
            #pragma unroll
            for (int q = 0; q < 4; q++) {
                float gxv = (float)(xp+q)*step - 1.0f;
                float u = gxv + sx;
                float xim = ((u + 1.0f)*0.5f)*959.0f;
                xims[q] = xim;
                // Early reject: rotation is an isometry; the 4 translation taps
                // lie within sqrt(2) px of the rotated center; >1.5 px outside
                // the active window -> every sampled value exactly 0.
                float gxc = xim*step - 1.0f;
                float uc = ct*gxc - sn*gyc;
                float vc = sn*gxc + ct*gyc;
                float xc2 = ((uc + 1.0f)*0.5f)*959.0f;
                float yc2 = ((vc + 1.0f)*0.5f)*959.0f;
                bool aa = (xc2 > 427.5f) && (xc2 < 531.5f) &&
                          (yc2 > 477.5f) && (yc2 < 581.5f);
                act[q] = aa;
                any = any || aa;
            }
            if (!any) {
                #pragma unroll
                for (int c = 0; c < 9; c++) {
                    float4 ml = *(const float4*)(maps_last + c*MPIX + p);
                    float4 o;
                    o.x = fmaxf(ml.x, 0.0f); o.y = fmaxf(ml.y, 0.0f);
                    o.z = fmaxf(ml.z, 0.0f); o.w = fmaxf(ml.w, 0.0f);
                    *(float4*)(out_map + c*MPIX + p) = o;
                }
                continue;
            }
            #pragma unroll
            for (int q = 0; q < 4; q++) {
                int o = p + q;
                float ts[7] = {0,0,0,0,0,0,0};
                if (act[q]) pixel_ts(xims[q], yim, ct, sn, sm, ts);
                float ml;
                ml = maps_last[0*MPIX + o]; out_map[0*MPIX + o] = fmaxf(ml, ts[0]);
                ml = maps_last[1*MPIX + o]; out_map[1*MPIX + o] = fmaxf(ml, ts[1]);
                ml = maps_last[2*MPIX + o]; out_map[2*MPIX + o] = fmaxf(ml, 0.0f);
                ml = maps_last[3*MPIX + o]; out_map[3*MPIX + o] = fmaxf(ml, 0.0f);
                float t4 = ts[2]; t4 = (t4 > 0.0f) ? ks0 : t4;
                ml = maps_last[4*MPIX + o]; out_map[4*MPIX + o] = fmaxf(ml, t4);
                float t5 = ts[3]; t5 = (t5 > 0.0f) ? ks1 : t5;
                ml = maps_last[5*MPIX + o]; out_map[5*MPIX + o] = fmaxf(ml, t5);
                float t6 = ts[4]; t6 = (t6 > 0.0f) ? ks2 : t6;
                ml = maps_last[6*MPIX + o]; out_map[6*MPIX + o] = fmaxf(ml, t6);
                float t7 = ts[5]; t7 = (t7 > 0.0f) ? ks3 : t7;
                ml = maps_last[7*MPIX + o]; out_map[7*MPIX + o] = fmaxf(ml, t7);
                ml = maps_last[8*MPIX + o]; out_map[8*MPIX + o] = fmaxf(ml, ts[6]);
            }
        }
    }
}

extern "C" void kernel_launch(void* const* d_in, const int* in_sizes, int n_in,
                              void* d_out, int out_size, void* d_ws, size_t ws_size,
                              hipStream_t stream) {
    const float* obs        = (const float*)d_in[0];
    const float* pose_obs   = (const float*)d_in[1];
    const float* maps_last  = (const float*)d_in[2];
    const float* poses_last = (const float*)d_in[3];
    float* out = (float*)d_out;

    unsigned* ws_u = (unsigned*)d_ws;
    float*    ws_f = (float*)d_ws;
    unsigned* cnt  = ws_u + CNT_OFF;
    float*    scal = ws_f + SCAL_OFF;
    unsigned* offs = ws_u + OFFS_OFF;
    float*    sm   = ws_f + SM_OFF;
    unsigned* pack = ws_u + PACK_OFF;
    float4*   pay  = (float4*)(ws_f + PAY_OFF);
    float*    out_fp   = out + OUT_FPMAP;
    float*    out_map  = out + OUT_MAP;
    float*    out_pose = out + OUT_POSE;

    float fcam = (float)(320.0 / tan(39.5 * M_PI / 180.0));

    // co-residency cap for cooperative launch (grid-stride loops tolerate any size)
    int perCU = 0;
    if (hipOccupancyMaxActiveBlocksPerMultiprocessor(&perCU, mega_kernel, 256, 0)
            != hipSuccess || perCU < 1)
        perCU = 2;
    int nblk = perCU * 256;          // 256 CUs on MI355X
    if (nblk > 1024) nblk = 1024;

    void* params[] = {
        (void*)&obs, (void*)&pose_obs, (void*)&maps_last, (void*)&poses_last,
        (void*)&cnt, (void*)&scal, (void*)&offs, (void*)&sm,
        (void*)&pack, (void*)&pay, (void*)&out_fp, (void*)&out_map,
        (void*)&out_pose, (void*)&fcam
    };
    hipError_t err = hipLaunchCooperativeKernel((const void*)mega_kernel,
                                                dim3(nblk), dim3(256),
                                                params, 0, stream);
    if (err != hipSuccess) {         // retry smaller if co-residency rejected
        err = hipLaunchCooperativeKernel((const void*)mega_kernel,
                                         dim3(512), dim3(256), params, 0, stream);
        if (err != hipSuccess)
            hipLaunchCooperativeKernel((const void*)mega_kernel,
                                       dim3(256), dim3(256), params, 0, stream);
    }
}

// Round 8
// 265.359 us; speedup vs baseline: 2.5785x; 2.5785x over previous
//
#include <hip/hip_runtime.h>
#include <math.h>

#define NPIX (480*640)
#define MDIM 960
#define MPIX (MDIM*MDIM)
#define PACK_M 307201u

// ws layout (u32/f32 units from base)
#define CNT_OFF    0         // u32[10000]
#define SCAL_OFF   10000     // f32[16]
#define MEMSET_U32 10016     // zero cnt+scal only
#define OFFS_OFF   10016     // u32[10001] (+pad)
#define SM_OFF     20024     // f32[70000]: 7 planes * 10000
#define PACK_OFF   90024     // u32[NPIX]
#define PAY_OFF    397224    // f32[8*NPIX]; 397224*4 % 16 == 0

// output layout (floats)
#define OUT_FPMAP 0
#define OUT_MAP   10000
#define OUT_POSE  (10000 + 9*MPIX)

// ---------------- count + ks (fused, 4 px/thread) ----------------
__global__ __launch_bounds__(256) void count_ks_kernel(const float* __restrict__ obs,
                                                       unsigned* __restrict__ cnt,
                                                       unsigned* __restrict__ pack,
                                                       float* scal, float fcam) {
    int g = blockIdx.x*256 + threadIdx.x;          // 0..76799
    int p = g*4;
    int i = p / 640, j0 = p - i*640;               // 4 pixels share a row (640%4==0)
    float4 d4 = *(const float4*)(obs + 3*NPIX + p);
    float dv[4] = {d4.x, d4.y, d4.z, d4.w};
    #pragma unroll
    for (int q = 0; q < 4; q++) {
        float d = dv[q];
        float X = ((float)(j0+q) - 319.5f) * d / fcam + 250.0f;
        float Z = ((float)(479 - i) - 239.5f) * d / fcam + 88.0f;
        float xs = ((X/5.0f - 50.0f)/100.0f)*2.0f;
        float ys = ((d/5.0f - 50.0f)/100.0f)*2.0f;
        float zs = ((Z/5.0f - 32.0f)/80.0f)*2.0f;
        float pos0 = (xs*100.0f)/2.0f + 50.0f;
        float pos1 = (ys*100.0f)/2.0f + 50.0f;
        float pos2 = (zs*80.0f)/2.0f + 40.0f;
        int bx = (int)floorf(pos0), by = (int)floorf(pos1), bz = (int)floorf(pos2);
        unsigned pk = 0xFFFFFFFFu;
        if (bx >= 0 && bx <= 99 && by >= 0 && by <= 99 && bz >= 0 && bz <= 79) {
            unsigned b = (unsigned)(bx*100 + by);
            unsigned rank = atomicAdd(&cnt[b], 1u);
            pk = b * PACK_M + rank;
        }
        pack[p+q] = pk;
    }
    // ks channel maxima (obs values nonnegative)
    float4 a = *(const float4*)(obs + 4*NPIX + p);
    float4 b4 = *(const float4*)(obs + 5*NPIX + p);
    float4 c4 = *(const float4*)(obs + 6*NPIX + p);
    float4 e4 = *(const float4*)(obs + 7*NPIX + p);
    float m0 = fmaxf(fmaxf(a.x,a.y), fmaxf(a.z,a.w));
    float m1 = fmaxf(fmaxf(b4.x,b4.y), fmaxf(b4.z,b4.w));
    float m2 = fmaxf(fmaxf(c4.x,c4.y), fmaxf(c4.z,c4.w));
    float m3 = fmaxf(fmaxf(e4.x,e4.y), fmaxf(e4.z,e4.w));
    #pragma unroll
    for (int off = 32; off > 0; off >>= 1) {
        m0 = fmaxf(m0, __shfl_down(m0, off, 64));
        m1 = fmaxf(m1, __shfl_down(m1, off, 64));
        m2 = fmaxf(m2, __shfl_down(m2, off, 64));
        m3 = fmaxf(m3, __shfl_down(m3, off, 64));
    }
    if ((threadIdx.x & 63) == 0) {
        atomicMax((int*)&scal[4], __float_as_int(m0));
        atomicMax((int*)&scal[5], __float_as_int(m1));
        atomicMax((int*)&scal[6], __float_as_int(m2));
        atomicMax((int*)&scal[7], __float_as_int(m3));
    }
}

// ---------------- scan (256 threads, one WG) + pose fused ----------------
__global__ __launch_bounds__(256) void scan_pose_kernel(const unsigned* __restrict__ cnt,
                                                        unsigned* __restrict__ offs,
                                                        const float* pose_obs,
                                                        const float* poses_last,
                                                        float* scal, float* out_pose) {
    int tid = threadIdx.x;
    int lane = tid & 63, wave = tid >> 6;
    unsigned sum = 0;
    #pragma unroll 4
    for (int q = 0; q < 40; q++) {
        int idx = tid*40 + q;
        if (idx < 10000) sum += cnt[idx];
    }
    unsigned incl = sum;
    #pragma unroll
    for (int off = 1; off < 64; off <<= 1) {
        unsigned u = (unsigned)__shfl_up((int)incl, off, 64);
        if (lane >= off) incl += u;
    }
    __shared__ unsigned wtot[4];
    if (lane == 63) wtot[wave] = incl;
    __syncthreads();
    unsigned pre = 0;
    for (int w = 0; w < wave; w++) pre += wtot[w];
    unsigned excl = pre + incl - sum;
    unsigned run = excl;
    #pragma unroll 4
    for (int q = 0; q < 40; q++) {
        int idx = tid*40 + q;
        if (idx < 10000) { offs[idx] = run; run += cnt[idx]; }
    }
    if (tid == 255) {
        offs[10000] = excl;   // == grand total (threads 250..255 contribute 0)
        const float DEGc = 57.29577951308232f;
        float th = poses_last[2] / DEGc;
        float s = sinf(th), c = cosf(th);
        float ny = poses_last[1] + pose_obs[0]*s + pose_obs[1]*c;
        float nx = poses_last[0] + pose_obs[0]*c - pose_obs[1]*s;
        float nt = poses_last[2] + pose_obs[2]*DEGc;
        nt = fmodf(nt - 180.0f, 360.0f) + 180.0f;
        nt = fmodf(nt + 180.0f, 360.0f) - 180.0f;
        out_pose[0] = nx; out_pose[1] = ny; out_pose[2] = nt;
        out_pose[3] = nx; out_pose[4] = ny; out_pose[5] = nt;
        float sx = -((nx*100.0f)/5.0f - 480.0f)/480.0f;
        float sy = -((ny*100.0f)/5.0f - 480.0f)/480.0f;
        float sth = ((90.0f - nt) * 3.14159265358979323846f) / 180.0f;
        scal[0] = cosf(sth);
        scal[1] = sinf(sth);
        scal[2] = sx;
        scal[3] = sy;
    }
}

// ---------------- scatter (atomic-free, 4 px/thread) ----------------
__global__ __launch_bounds__(256) void scatter_kernel(const float* __restrict__ obs,
                                                      const unsigned* __restrict__ offs,
                                                      const unsigned* __restrict__ pack,
                                                      float4* __restrict__ pay, float fcam) {
    int g = blockIdx.x*256 + threadIdx.x;
    int p = g*4;
    int i = p / 640, j0 = p - i*640;
    uint4 pk4 = *(const uint4*)(pack + p);
    unsigned pks[4] = {pk4.x, pk4.y, pk4.z, pk4.w};
    float4 d4 = *(const float4*)(obs + 3*NPIX + p);
    float4 f14 = *(const float4*)(obs + 4*NPIX + p);
    float4 f24 = *(const float4*)(obs + 5*NPIX + p);
    float4 f34 = *(const float4*)(obs + 6*NPIX + p);
    float4 f44 = *(const float4*)(obs + 7*NPIX + p);
    float4 f54 = *(const float4*)(obs + 8*NPIX + p);
    float dv[4] = {d4.x, d4.y, d4.z, d4.w};
    float f1[4] = {f14.x, f14.y, f14.z, f14.w};
    float f2[4] = {f24.x, f24.y, f24.z, f24.w};
    float f3[4] = {f34.x, f34.y, f34.z, f34.w};
    float f4v[4] = {f44.x, f44.y, f44.z, f44.w};
    float f5[4] = {f54.x, f54.y, f54.z, f54.w};
    #pragma unroll
    for (int q = 0; q < 4; q++) {
        unsigned pk = pks[q];
        if (pk == 0xFFFFFFFFu) continue;
        unsigned b = pk / PACK_M;
        unsigned rank = pk - b * PACK_M;
        unsigned k = offs[b] + rank;
        float d = dv[q];
        float X = ((float)(j0+q) - 319.5f) * d / fcam + 250.0f;
        float Z = ((float)(479 - i) - 239.5f) * d / fcam + 88.0f;
        float xs = ((X/5.0f - 50.0f)/100.0f)*2.0f;
        float ys = ((d/5.0f - 50.0f)/100.0f)*2.0f;
        float zs = ((Z/5.0f - 32.0f)/80.0f)*2.0f;
        float pos0 = (xs*100.0f)/2.0f + 50.0f;
        float pos1 = (ys*100.0f)/2.0f + 50.0f;
        float pos2 = (zs*80.0f)/2.0f + 40.0f;
        pay[2*k + 0] = make_float4(pos0, pos1, pos2, f1[q]);
        pay[2*k + 1] = make_float4(f2[q], f3[q], f4v[q], f5[q]);
    }
}

// ---------------- gather: 2500 WGs x 256 thr; 1 wave = 1 column ----------------
// Per-wave private LDS slab (488-stride pads banks); 2 contiguous bin segments;
// channels 1-5 accumulated only for z in [13,25) (never read outside).
__global__ __launch_bounds__(256) void gather_kernel(const float4* __restrict__ pay,
                                                     const unsigned* __restrict__ offs,
                                                     float* __restrict__ sm,
                                                     float* __restrict__ out_fp) {
    int wave = threadIdx.x >> 6, lane = threadIdx.x & 63;
    int t = blockIdx.x*4 + wave;       // 2500*4 = 10000 exactly
    int x = t % 100, y = t / 100;
    __shared__ float slabs[4][488];
    float* za = slabs[wave];
    for (int q = lane; q < 480; q += 64) za[q] = 0.0f;
    __syncthreads();
    if (x >= 1 && y >= 1) {            // x==0 or y==0: no in-bounds corners (safe=0)
        int bb0 = (x-1)*100 + (y-1);   // bins (x-1,y-1),(x-1,y) contiguous
        int bb1 = x*100 + (y-1);       // bins (x,y-1),(x,y) contiguous
        #pragma unroll
        for (int sgi = 0; sgi < 2; sgi++) {
            int b = sgi ? bb1 : bb0;
            unsigned s = offs[b], e = offs[b+2];
            for (unsigned k = s + lane; k < e; k += 64) {
                float4 a  = pay[2*k + 0];
                float4 q2 = pay[2*k + 1];
                // weights replicate reference order: ((1*(1-|d0|))*(1-|d1|))*(1-|d2|)
                float w0 = 1.0f - fabsf(a.x - (float)x);
                float w1 = 1.0f - fabsf(a.y - (float)y);
                float w01 = w0 * w1;
                float bzf = floorf(a.z);
                #pragma unroll
                for (int c2 = 0; c2 <= 1; c2++) {
                    float p2 = bzf + (float)c2;
                    if (!(p2 > 0.0f && p2 < 80.0f)) continue;
                    float w = w01 * (1.0f - fabsf(a.z - p2));
                    int zi = (int)p2;
                    int zb = zi * 6;
                    atomicAdd(&za[zb + 0], w);
                    if (zi >= 13 && zi < 25) {
                        atomicAdd(&za[zb + 1], w*a.w);
                        atomicAdd(&za[zb + 2], w*q2.x);
                        atomicAdd(&za[zb + 3], w*q2.y);
                        atomicAdd(&za[zb + 4], w*q2.z);
                        atomicAdd(&za[zb + 5], w*q2.w);
                    }
                }
            }
        }
    }
    __syncthreads();
    // per-z round, then column sums (exact: summands are small integers)
    int z = lane;                      // z in [0,64); [64,80) folded by lanes 0..15
    float r0 = rintf(za[z*6 + 0]);
    float all0 = r0;
    if (lane < 16) all0 += rintf(za[(z + 64)*6 + 0]);
    bool inb = (z >= 13 && z < 25);
    float a0 = inb ? r0 : 0.0f;
    float a1 = inb ? rintf(za[z*6 + 1]) : 0.0f;
    float a2 = inb ? rintf(za[z*6 + 2]) : 0.0f;
    float a3 = inb ? rintf(za[z*6 + 3]) : 0.0f;
    float a4 = inb ? rintf(za[z*6 + 4]) : 0.0f;
    float a5 = inb ? rintf(za[z*6 + 5]) : 0.0f;
    #pragma unroll
    for (int off = 32; off > 0; off >>= 1) {
        all0 += __shfl_down(all0, off, 64);
        a0 += __shfl_down(a0, off, 64);
        a1 += __shfl_down(a1, off, 64);
        a2 += __shfl_down(a2, off, 64);
        a3 += __shfl_down(a3, off, 64);
        a4 += __shfl_down(a4, off, 64);
        a5 += __shfl_down(a5, off, 64);
    }
    if (lane == 0) {
        float fp = fminf(a0, 1.0f);
        float ex = fminf(all0, 1.0f);
        sm[0*10000 + t] = fp;
        sm[1*10000 + t] = ex;
        sm[2*10000 + t] = fminf(a1/5.0f, 1.0f);
        sm[3*10000 + t] = fminf(a2/5.0f, 1.0f);
        sm[4*10000 + t] = fminf(a3/5.0f, 1.0f);
        sm[5*10000 + t] = fminf(a4/5.0f, 1.0f);
        sm[6*10000 + t] = fminf(a5/5.0f, 1.0f);
        out_fp[t] = fp;
    }
}

// bilinear sample of the (implicit, mostly-zero) agent_view at normalized coords
__device__ __forceinline__ void sample_agent(float gxv, float gyv,
                                             float ct, float sn,
                                             const float* __restrict__ sm,
                                             float rot[7]) {
    float u = ct*gxv - sn*gyv;
    float v = sn*gxv + ct*gyv;
    float xim = ((u + 1.0f)*0.5f)*959.0f;
    float yim = ((v + 1.0f)*0.5f)*959.0f;
    float x0 = floorf(xim), y0 = floorf(yim);
    #pragma unroll
    for (int ty = 0; ty <= 1; ty++) {
        float yy = y0 + (float)ty;
        if (yy < 480.0f || yy >= 580.0f) continue;   // region rows [480,580)
        float wy = 1.0f - fabsf(yim - yy);
        int yi = (int)yy - 480;
        #pragma unroll
        for (int tx = 0; tx <= 1; tx++) {
            float xx = x0 + (float)tx;
            if (xx < 430.0f || xx >= 530.0f) continue;  // region cols [430,530)
            float w = (1.0f - fabsf(xim - xx)) * wy;
            int o = yi*100 + ((int)xx - 430);
            #pragma unroll
            for (int k = 0; k < 7; k++) rot[k] += sm[k*10000 + o] * w;
        }
    }
}

__device__ __forceinline__ void pixel_ts(float xim, float yim, float ct, float sn,
                                         const float* __restrict__ sm, float ts[7]) {
    const float step = 2.0f/959.0f;
    float x0 = floorf(xim), y0 = floorf(yim);
    #pragma unroll
    for (int ty = 0; ty <= 1; ty++) {
        float yy = y0 + (float)ty;
        if (yy < 0.0f || yy > 959.0f) continue;
        float wy = 1.0f - fabsf(yim - yy);
        #pragma unroll
        for (int tx = 0; tx <= 1; tx++) {
            float xx = x0 + (float)tx;
            if (xx < 0.0f || xx > 959.0f) continue;
            float w = (1.0f - fabsf(xim - xx)) * wy;
            float rot[7] = {0,0,0,0,0,0,0};
            float gx1 = xx*step - 1.0f;
            float gy1 = yy*step - 1.0f;
            sample_agent(gx1, gy1, ct, sn, sm, rot);
            #pragma unroll
            for (int k = 0; k < 7; k++) ts[k] += rot[k]*w;
        }
    }
}

// ---------------- final: 4 px/thread, float4 fast path ----------------
__global__ __launch_bounds__(256) void final_kernel(const float* __restrict__ maps_last,
                                                    const float* __restrict__ sm,
                                                    const float* __restrict__ scal,
                                                    float* __restrict__ out_map) {
    int g = blockIdx.x*256 + threadIdx.x;    // 0..230399
    int p = g*4;
    int y = p / MDIM, xp = p - y*MDIM;       // 4 pixels share a row (960%4==0)
    float ct = scal[0], sn = scal[1], sx = scal[2], sy = scal[3];
    const float step = 2.0f/959.0f;
    float gyv = (float)y*step - 1.0f;
    float v = gyv + sy;
    float yim = ((v + 1.0f)*0.5f)*959.0f;
    float gyc = yim*step - 1.0f;
    float xims[4];
    bool act[4];
    bool any = false;
    #pragma unroll
    for (int q = 0; q < 4; q++) {
        float gxv = (float)(xp+q)*step - 1.0f;
        float u = gxv + sx;
        float xim = ((u + 1.0f)*0.5f)*959.0f;
        xims[q] = xim;
        // Early reject: rotation is an isometry; the 4 translation taps lie
        // within sqrt(2) px of the rotated center; >1.5 px outside the active
        // window (rows (479,580), cols (429,530)) -> every sample exactly 0.
        float gxc = xim*step - 1.0f;
        float uc = ct*gxc - sn*gyc;
        float vc = sn*gxc + ct*gyc;
        float xc2 = ((uc + 1.0f)*0.5f)*959.0f;
        float yc2 = ((vc + 1.0f)*0.5f)*959.0f;
        bool a = (xc2 > 427.5f) && (xc2 < 531.5f) && (yc2 > 477.5f) && (yc2 < 581.5f);
        act[q] = a;
        any = any || a;
    }
    if (!any) {
        // ts == 0 exactly for all 4 pixels: every channel -> max(ml, 0)
        #pragma unroll
        for (int c = 0; c < 9; c++) {
            float4 ml = *(const float4*)(maps_last + c*MPIX + p);
            float4 o;
            o.x = fmaxf(ml.x, 0.0f); o.y = fmaxf(ml.y, 0.0f);
            o.z = fmaxf(ml.z, 0.0f); o.w = fmaxf(ml.w, 0.0f);
            *(float4*)(out_map + c*MPIX + p) = o;
        }
        return;
    }
    float ks0 = scal[4], ks1 = scal[5], ks2 = scal[6], ks3 = scal[7];
    #pragma unroll
    for (int q = 0; q < 4; q++) {
        int o = p + q;
        float ts[7] = {0,0,0,0,0,0,0};
        if (act[q]) pixel_ts(xims[q], yim, ct, sn, sm, ts);
        float ml;
        ml = maps_last[0*MPIX + o]; out_map[0*MPIX + o] = fmaxf(ml, ts[0]);
        ml = maps_last[1*MPIX + o]; out_map[1*MPIX + o] = fmaxf(ml, ts[1]);
        ml = maps_last[2*MPIX + o]; out_map[2*MPIX + o] = fmaxf(ml, 0.0f);
        ml = maps_last[3*MPIX + o]; out_map[3*MPIX + o] = fmaxf(ml, 0.0f);
        float t4 = ts[2]; t4 = (t4 > 0.0f) ? ks0 : t4;
        ml = maps_last[4*MPIX + o]; out_map[4*MPIX + o] = fmaxf(ml, t4);
        float t5 = ts[3]; t5 = (t5 > 0.0f) ? ks1 : t5;
        ml = maps_last[5*MPIX + o]; out_map[5*MPIX + o] = fmaxf(ml, t5);
        float t6 = ts[4]; t6 = (t6 > 0.0f) ? ks2 : t6;
        ml = maps_last[6*MPIX + o]; out_map[6*MPIX + o] = fmaxf(ml, t6);
        float t7 = ts[5]; t7 = (t7 > 0.0f) ? ks3 : t7;
        ml = maps_last[7*MPIX + o]; out_map[7*MPIX + o] = fmaxf(ml, t7);
        ml = maps_last[8*MPIX + o]; out_map[8*MPIX + o] = fmaxf(ml, ts[6]);
    }
}

extern "C" void kernel_launch(void* const* d_in, const int* in_sizes, int n_in,
                              void* d_out, int out_size, void* d_ws, size_t ws_size,
                              hipStream_t stream) {
    const float* obs        = (const float*)d_in[0];
    const float* pose_obs   = (const float*)d_in[1];
    const float* maps_last  = (const float*)d_in[2];
    const float* poses_last = (const float*)d_in[3];
    float* out = (float*)d_out;

    unsigned* ws_u = (unsigned*)d_ws;
    float*    ws_f = (float*)d_ws;
    unsigned* cnt  = ws_u + CNT_OFF;
    float*    scal = ws_f + SCAL_OFF;
    unsigned* offs = ws_u + OFFS_OFF;
    float*    sm   = ws_f + SM_OFF;
    unsigned* pack = ws_u + PACK_OFF;
    float4*   pay  = (float4*)(ws_f + PAY_OFF);

    // zero cnt + scal (40 KB; ws is poisoned 0xAA each launch)
    hipMemsetAsync(d_ws, 0, (size_t)MEMSET_U32 * 4, stream);

    float fcam = (float)(320.0 / tan(39.5 * M_PI / 180.0));

    count_ks_kernel<<<300, 256, 0, stream>>>(obs, cnt, pack, scal, fcam);
    scan_pose_kernel<<<1, 256, 0, stream>>>(cnt, offs, pose_obs, poses_last,
                                            scal, out + OUT_POSE);
    scatter_kernel<<<300, 256, 0, stream>>>(obs, offs, pack, pay, fcam);
    gather_kernel<<<2500, 256, 0, stream>>>(pay, offs, sm, out + OUT_FPMAP);
    final_kernel<<<900, 256, 0, stream>>>(maps_last, sm, scal, out + OUT_MAP);
}